// Round 5
// baseline (201.192 us; speedup 1.0000x reference)
//
#include <hip/hip_runtime.h>
#include <math.h>

// GCN is linear: out = (((z3^T X) W1 + s2 b1) W2 + s1 b2) W3 + N b3) / sqrt(N)
// z_{l+1} = M^T z_l via gather over slot entries keyed by src; p_l = dinv.*z_l.
// Inherited laws (r7-r17):
//   (1) returning random atomics 13.3 G/s alone; non-returning ~50 G/s
//       marginal when mixed — cheap, not free
//   (2) same-address atomics ~13 ns each, serialized (<1k block-adds ok)
//   (3) in-kernel device-scope fences poison resident L2 -> kernel boundary
//       is the only cheap device-wide sync
//   (4) random 4B L2 gathers ~free   (5) ~3.5 us per dispatch boundary
//   (6) micro-restructurings of the latency-class kernels regress
//   (7) latency kernels need >=2-3 blocks/CU; 200 blocks @ 32KB LDS = 7%
//       occupancy exposed every latency in hist2 (r16: 41 us)
//   (8) r17: HCHUNKS=32 grew workspace to 55.8MB -> container died twice.
//       NEVER exceed the r16-proven 36.6MB footprint without checking ws_size.
// ROUND 18: occupancy fix with ZERO extra memory: RBINS 4096->1024 =>
//   NR=98, grid 98x8=784 blocks (~3/CU, ~12 waves/CU), LDS 8KB/block.
//   Redundant scan 98x4.8MB = 470MB but L2/L3-resident (~13 us of BW).
//   Everything else byte-identical to r16 (195.4 us measured).

#define TPB 256
#define KSLOT 64
#define RBINS 1024     // bins per histogram block -> 2x4KB LDS
#define HCHUNKS 8      // edge chunks (keeps pdeg arrays at r16 size)

__device__ __forceinline__ float dinv_of(int degv) {
    return (float)(1.0 / sqrt((double)degv + 1.0));
}

// Block = (range r, chunk c): scan chunk c of (src,dst) once.
//   src in range: rank[e] = atomicAdd(&hs[s-lo],1)  (LDS returning atomic)
//   dst in range: atomicAdd(&hd[d-lo],1)
// Store per-chunk counts: pdeg_src[c][i], pdeg_dst[c][i]. No global atomics.
__global__ void k_hist2(const int* __restrict__ src, const int* __restrict__ dst,
                        int* __restrict__ pdeg_src, int* __restrict__ pdeg_dst,
                        int* __restrict__ rank, int E, int N, int EC, int NRANGE) {
    __shared__ int hs[RBINS];
    __shared__ int hd[RBINS];
    int r = blockIdx.x / HCHUNKS;
    int c = blockIdx.x % HCHUNKS;
    int lo = r * RBINS;
    for (int k = threadIdx.x; k < RBINS; k += TPB) { hs[k] = 0; hd[k] = 0; }
    __syncthreads();
    int e0 = c * EC;
    int e1 = e0 + EC; if (e1 > E) e1 = E;
    if (e0 < e1) {
        int n4 = (e1 - e0) >> 2;
        const int4* ps = (const int4*)(src + e0);
        const int4* pd = (const int4*)(dst + e0);
        int j = threadIdx.x;
        for (; j + TPB < n4; j += 2 * TPB) {           // 4 loads in flight
            int4 s0 = ps[j], s1 = ps[j + TPB];
            int4 d0 = pd[j], d1 = pd[j + TPB];
            int eb0 = e0 + (j << 2), eb1 = e0 + ((j + TPB) << 2);
            int a;
            a = s0.x - lo; if ((unsigned)a < RBINS) rank[eb0 + 0] = atomicAdd(&hs[a], 1);
            a = s0.y - lo; if ((unsigned)a < RBINS) rank[eb0 + 1] = atomicAdd(&hs[a], 1);
            a = s0.z - lo; if ((unsigned)a < RBINS) rank[eb0 + 2] = atomicAdd(&hs[a], 1);
            a = s0.w - lo; if ((unsigned)a < RBINS) rank[eb0 + 3] = atomicAdd(&hs[a], 1);
            a = s1.x - lo; if ((unsigned)a < RBINS) rank[eb1 + 0] = atomicAdd(&hs[a], 1);
            a = s1.y - lo; if ((unsigned)a < RBINS) rank[eb1 + 1] = atomicAdd(&hs[a], 1);
            a = s1.z - lo; if ((unsigned)a < RBINS) rank[eb1 + 2] = atomicAdd(&hs[a], 1);
            a = s1.w - lo; if ((unsigned)a < RBINS) rank[eb1 + 3] = atomicAdd(&hs[a], 1);
            a = d0.x - lo; if ((unsigned)a < RBINS) atomicAdd(&hd[a], 1);
            a = d0.y - lo; if ((unsigned)a < RBINS) atomicAdd(&hd[a], 1);
            a = d0.z - lo; if ((unsigned)a < RBINS) atomicAdd(&hd[a], 1);
            a = d0.w - lo; if ((unsigned)a < RBINS) atomicAdd(&hd[a], 1);
            a = d1.x - lo; if ((unsigned)a < RBINS) atomicAdd(&hd[a], 1);
            a = d1.y - lo; if ((unsigned)a < RBINS) atomicAdd(&hd[a], 1);
            a = d1.z - lo; if ((unsigned)a < RBINS) atomicAdd(&hd[a], 1);
            a = d1.w - lo; if ((unsigned)a < RBINS) atomicAdd(&hd[a], 1);
        }
        for (; j < n4; j += TPB) {
            int4 sv = ps[j], dv = pd[j];
            int eb = e0 + (j << 2);
            int a;
            a = sv.x - lo; if ((unsigned)a < RBINS) rank[eb + 0] = atomicAdd(&hs[a], 1);
            a = sv.y - lo; if ((unsigned)a < RBINS) rank[eb + 1] = atomicAdd(&hs[a], 1);
            a = sv.z - lo; if ((unsigned)a < RBINS) rank[eb + 2] = atomicAdd(&hs[a], 1);
            a = sv.w - lo; if ((unsigned)a < RBINS) rank[eb + 3] = atomicAdd(&hs[a], 1);
            a = dv.x - lo; if ((unsigned)a < RBINS) atomicAdd(&hd[a], 1);
            a = dv.y - lo; if ((unsigned)a < RBINS) atomicAdd(&hd[a], 1);
            a = dv.z - lo; if ((unsigned)a < RBINS) atomicAdd(&hd[a], 1);
            a = dv.w - lo; if ((unsigned)a < RBINS) atomicAdd(&hd[a], 1);
        }
        for (int t = e0 + (n4 << 2) + threadIdx.x; t < e1; t += TPB) {
            int a = src[t] - lo; if ((unsigned)a < RBINS) rank[t] = atomicAdd(&hs[a], 1);
            a = dst[t] - lo;     if ((unsigned)a < RBINS) atomicAdd(&hd[a], 1);
        }
    }
    __syncthreads();
    for (int k = threadIdx.x; k < RBINS; k += TPB) {
        int g = lo + k;
        if (g < N) {
            pdeg_src[(size_t)c * N + g] = hs[k];
            pdeg_dst[(size_t)c * N + g] = hd[k];
        }
    }
}

// dinvf from dst-count sum; exclusive chunk-prefix of src-counts IN PLACE
// (pdeg_src becomes base); cnt[i] = total src count. Also zeroes sig.
__global__ void k_merge2(int* __restrict__ pdeg_src, const int* __restrict__ pdeg_dst,
                         int* __restrict__ cnt, float* __restrict__ dinvf,
                         float* __restrict__ sig, int N) {
    int i = blockIdx.x * blockDim.x + threadIdx.x;
    if (i < 4) sig[i] = 0.0f;                     // absorbs the memset dispatch
    if (i < N) {
        int sd = 0;
        #pragma unroll
        for (int c = 0; c < HCHUNKS; ++c) sd += pdeg_dst[(size_t)c * N + i];
        dinvf[i] = dinv_of(sd);
        int run = 0;
        #pragma unroll
        for (int c = 0; c < HCHUNKS; ++c) {
            int v = pdeg_src[(size_t)c * N + i];
            pdeg_src[(size_t)c * N + i] = run;
            run += v;
        }
        cnt[i] = run;
    }
}

// slots_t[pos*N + s] = d with pos = base[chunk(e)][s] + rank[e]. No atomics;
// coalesced reads + one random 4B gather (base) + one random 4B store.
__global__ void k_scatter(const int* __restrict__ src, const int* __restrict__ dst,
                          const int* __restrict__ rank, const int* __restrict__ base,
                          int* __restrict__ slots_t, int E, int N, int EC) {
    int e = blockIdx.x * blockDim.x + threadIdx.x;
    if (e < E) {
        int s = src[e], d = dst[e];
        int c = e / EC;
        int pos = base[(size_t)c * N + s] + rank[e];
        if (pos < KSLOT) slots_t[(size_t)pos * N + s] = d;
    }
}

// One propagation layer (1 thread/node), TRANSPOSED coalesced slot reads:
//   q      = sum_{r<cnt[i]} pin[slots_t[r*N+i]]   (layer 1: pin = dinvf)
//   z[i]   = dinv*(q + dinv*zprev)                (first => zprev=1, else z[i])
//   p_out  = dinv*z[i]  (if p_out)  ;  *sig += sum(z)  (if sig)
__global__ void k_qfin(const float* __restrict__ dinvf, const int* __restrict__ cnt,
                       const int* __restrict__ slots_t, const float* __restrict__ pin,
                       float* __restrict__ z, float* __restrict__ p_out,
                       float* __restrict__ sig, int first, int N) {
    __shared__ float red[TPB];
    int i = blockIdx.x * blockDim.x + threadIdx.x;
    float zv = 0.0f;
    if (i < N) {
        int c = cnt[i];
        if (c > KSLOT) c = KSLOT;
        float q = 0.0f;
        int r = 0;
        for (; r + 4 <= c; r += 4) {                  // 4 gathers in flight
            int j0 = slots_t[(size_t)(r + 0) * N + i];
            int j1 = slots_t[(size_t)(r + 1) * N + i];
            int j2 = slots_t[(size_t)(r + 2) * N + i];
            int j3 = slots_t[(size_t)(r + 3) * N + i];
            q += pin[j0] + pin[j1] + pin[j2] + pin[j3];
        }
        for (; r < c; ++r) q += pin[slots_t[(size_t)r * N + i]];
        float dv = dinvf[i];
        float zprev = first ? 1.0f : z[i];
        zv = dv * (q + dv * zprev);
        z[i] = zv;
        if (p_out) p_out[i] = dv * zv;
    }
    if (sig) {
        red[threadIdx.x] = zv;
        __syncthreads();
        for (int s = TPB / 2; s > 0; s >>= 1) {
            if (threadIdx.x < s) red[threadIdx.x] += red[threadIdx.x + s];
            __syncthreads();
        }
        if (threadIdx.x == 0) unsafeAtomicAdd(sig, red[0]);
    }
}

// Layer 3 fused with the X reduction: block b computes z3 for its 256 rows
// (transposed gather, zprev = z2 in place, z3 store dead), then
// partials[b][0:128] = sum_{r in block} z3[r] * X[r][0:128].
__global__ void k_qfin3w(const float* __restrict__ dinvf, const int* __restrict__ cnt,
                         const int* __restrict__ slots_t, const float* __restrict__ pin,
                         const float* __restrict__ z, const float* __restrict__ x,
                         float* __restrict__ partials, int N) {
    __shared__ float zbuf[TPB];
    __shared__ float4 red4[TPB];
    int tid = threadIdx.x;
    int i = blockIdx.x * blockDim.x + tid;
    float zv = 0.0f;
    if (i < N) {
        int c = cnt[i];
        if (c > KSLOT) c = KSLOT;
        float q = 0.0f;
        int r = 0;
        for (; r + 4 <= c; r += 4) {
            int j0 = slots_t[(size_t)(r + 0) * N + i];
            int j1 = slots_t[(size_t)(r + 1) * N + i];
            int j2 = slots_t[(size_t)(r + 2) * N + i];
            int j3 = slots_t[(size_t)(r + 3) * N + i];
            q += pin[j0] + pin[j1] + pin[j2] + pin[j3];
        }
        for (; r < c; ++r) q += pin[slots_t[(size_t)r * N + i]];
        float dv = dinvf[i];
        zv = dv * (q + dv * z[i]);
    }
    zbuf[tid] = zv;
    __syncthreads();
    int base = blockIdx.x * TPB;
    int nrows = N - base; if (nrows > TPB) nrows = TPB;
    int c4 = (tid & 31) * 4;
    int rg = tid >> 5;                            // 8 row-groups
    float4 acc = make_float4(0.f, 0.f, 0.f, 0.f);
    for (int r = rg; r < nrows; r += 8) {
        float zr = zbuf[r];
        const float4 xv = *(const float4*)(x + (size_t)(base + r) * 128 + c4);
        acc.x += zr * xv.x; acc.y += zr * xv.y;
        acc.z += zr * xv.z; acc.w += zr * xv.w;
    }
    red4[tid] = acc;
    __syncthreads();
    if (tid < 32) {
        float4 a = red4[tid];
        #pragma unroll
        for (int g = 1; g < 8; ++g) {
            float4 b = red4[tid + 32 * g];
            a.x += b.x; a.y += b.y; a.z += b.z; a.w += b.w;
        }
        float* pp = partials + (size_t)blockIdx.x * 128 + c4;
        pp[0] = a.x; pp[1] = a.y; pp[2] = a.z; pp[3] = a.w;
    }
}

// 1024 threads: reduce partials -> u0, then 3-layer 128-wide chain.
__global__ __launch_bounds__(1024) void k_final(
        const float* __restrict__ partials, int nb,
        const float* __restrict__ Ws, const float* __restrict__ bs,
        const float* __restrict__ sig, float* __restrict__ out, int N) {
    __shared__ float uv[128];
    __shared__ float red[1024];
    int t = threadIdx.x;
    int j = t & 127, g = t >> 7;            // g in [0,8)
    float acc = 0.0f;
    for (int b = g; b < nb; b += 8) acc += partials[(size_t)b * 128 + j];
    red[t] = acc;
    __syncthreads();
    if (t < 128) {
        float s = 0.0f;
        #pragma unroll
        for (int gg = 0; gg < 8; ++gg) s += red[t + 128 * gg];
        uv[t] = s;
    }
    __syncthreads();
    float s1 = sig[0], s2 = sig[1];
    for (int l = 0; l < 3; ++l) {
        const float* W = Ws + (size_t)l * 16384;
        float a = 0.0f;
        #pragma unroll
        for (int kk = 0; kk < 16; ++kk) {
            int k = g * 16 + kk;
            a += uv[k] * W[k * 128 + j];
        }
        red[t] = a;
        __syncthreads();
        float nv = 0.0f;
        if (t < 128) {
            float s = 0.0f;
            #pragma unroll
            for (int gg = 0; gg < 8; ++gg) s += red[t + 128 * gg];
            float coef = (l == 0) ? s2 : (l == 1) ? s1 : (float)N;
            nv = s + coef * bs[l * 128 + t];
        }
        __syncthreads();
        if (t < 128) uv[t] = nv;
        __syncthreads();
    }
    if (t < 128) out[t] = uv[t] * (float)(1.0 / sqrt((double)N));
}

extern "C" void kernel_launch(void* const* d_in, const int* in_sizes, int n_in,
                              void* d_out, int out_size, void* d_ws, size_t ws_size,
                              hipStream_t stream) {
    const int*   ei = (const int*)d_in[0];
    const float* X  = (const float*)d_in[1];
    const float* Ws = (const float*)d_in[2];
    const float* bs = (const float*)d_in[3];
    float* out = (float*)d_out;

    int E = in_sizes[0] / 2;
    int N = in_sizes[1] / 128;
    const int* src = ei;
    const int* dst = ei + E;

    int gE = (E + TPB - 1) / TPB;
    int gN = (N + TPB - 1) / TPB;
    int NR = (N + RBINS - 1) / RBINS;               // 98 ranges @ N=100k
    int EC = ((E + HCHUNKS - 1) / HCHUNKS + 3) & ~3; // 16B-aligned chunks

    // layout (floats): [sig 4][cnt N][dinvf N][z N][pa N][pb N]
    //   [partials gN*128][pdeg_src HC*N][pdeg_dst HC*N][rank E][slots_t K*N]
    //   = 36.6 MB @ N=100k,E=600k (r16-proven footprint)
    float* ws       = (float*)d_ws;
    float* sig      = ws;                            // [4] zeroed by merge2
    int*   cnt      = (int*)(ws + 4);                // [N] by k_merge2
    float* dinvf    = ws + 4 + N;                    // [N] by k_merge2
    float* z        = ws + 4 + 2 * N;                // [N] z1 -> z2 in place
    float* pa       = z + N;                         // [N] p1
    float* pb       = pa + N;                        // [N] p2
    float* partials = pb + N;                        // [gN*128]
    int*   pdeg_src = (int*)(partials + (size_t)gN * 128);   // [HC*N] -> base
    int*   pdeg_dst = pdeg_src + (size_t)HCHUNKS * N;        // [HC*N]
    int*   rank     = pdeg_dst + (size_t)HCHUNKS * N;        // [E]
    int*   slots_t  = rank + E;                              // [KSLOT*N]

    k_hist2 <<<NR * HCHUNKS, TPB, 0, stream>>>(src, dst, pdeg_src, pdeg_dst,
                                               rank, E, N, EC, NR);
    k_merge2<<<gN, TPB, 0, stream>>>(pdeg_src, pdeg_dst, cnt, dinvf, sig, N);
    k_scatter<<<gE, TPB, 0, stream>>>(src, dst, rank, pdeg_src, slots_t, E, N, EC);
    // layer 1: pin = dinvf (z0 = 1); sig[0] = sum z1
    k_qfin <<<gN, TPB, 0, stream>>>(dinvf, cnt, slots_t, dinvf, z, pa, &sig[0], 1, N);
    // layer 2: pin = p1, zprev = z1 in place; sig[1] = sum z2
    k_qfin <<<gN, TPB, 0, stream>>>(dinvf, cnt, slots_t, pa, z, pb, &sig[1], 0, N);
    // layer 3 fused with X reduction (z3 never materialized)
    k_qfin3w<<<gN, TPB, 0, stream>>>(dinvf, cnt, slots_t, pb, z, X, partials, N);
    k_final <<<1, 1024, 0, stream>>>(partials, gN, Ws, bs, sig, out, N);
}